// Round 6
// baseline (524.188 us; speedup 1.0000x reference)
//
#include <hip/hip_runtime.h>
#include <hip/hip_bf16.h>

// KronLinear: out = x @ (sum_r kron(a_r, b_r)) + bias
// M=8192 tokens, K=4096=(i,k_b), N=4096=(j,l), RANK=64.
// R8: INSTRUMENTATION ROUND. prep is byte-identical to R5 (build_w LDS-dbuf,
// pack_x LDS-transpose). Changes:
//  (1) gemm split into two 256-block dispatches (bofs 0/256) -- free, since
//      the 512-block version already runs as 2 sequential batches at
//      1 block/CU; drops the rocprof top-5 threshold to ~122us so prep
//      kernels >122us finally report their own counters.
//  (2) pack_x launched TWICE (idempotent). With R5's b+p=230us and this
//      round's total = b + 2p + g1 + g2, both prep durations are solved:
//      p = (total - g1 - g2) - 230, b = 230 - p.
// Expected total ~474 + p (intentional, buys the decomposition).

#define M_DIM 8192
#define N_DIM 4096
#define K_DIM 4096
#define KT_COUNT 128   // K_DIM / 32

typedef __attribute__((ext_vector_type(8))) short short8;
typedef __attribute__((ext_vector_type(4))) float floatx4;

typedef __attribute__((address_space(1))) void gvoid_t;
typedef __attribute__((address_space(3))) void lvoid_t;

static __device__ __forceinline__ void gl_lds16(const void* g, const void* l) {
  __builtin_amdgcn_global_load_lds((gvoid_t*)(unsigned long long)g,
                                   (lvoid_t*)(unsigned int)(unsigned long long)l,
                                   16, 0, 0);
}

static __device__ __forceinline__ unsigned short f2bf(float f) {
  unsigned int u = __builtin_bit_cast(unsigned int, f);
  u = (u + 0x7fffu + ((u >> 16) & 1u)) >> 16;  // RNE
  return (unsigned short)u;
}

#define BAR() asm volatile("s_barrier" ::: "memory")
#define WAIT_VM(N) asm volatile("s_waitcnt vmcnt(" #N ")" ::: "memory")
#define WAIT_LGKM0() asm volatile("s_waitcnt lgkmcnt(0)" ::: "memory")

// ---------------------------------------------------------------------------
// build_w: wT[n=(j*64+l)][i*64+k_b] = sum_r a[r,i,j]*b[r,k_b,l]
// 2048 blocks x 256 threads. Block = (i, j0-group of 16, k0-group of 8).
// b-slice staged through LDS in 8 r-groups (16KB), double-buffered via
// global_load_lds. Wp blob (T0, kt) = 8KB: chunk (c*128+n), k=kt*32+c*8..+7.
// ---------------------------------------------------------------------------
__global__ __launch_bounds__(256) void build_w_kernel(
    const float* __restrict__ a, const float* __restrict__ b,
    unsigned short* __restrict__ Wp) {
  __shared__ float lds_a[1024];     // 4 KB: a[r][16 j]
  __shared__ float lds_b[2][4096];  // 2 x 16 KB: [8 r][512 (kb,l)]
  const int bid = blockIdx.x;
  const int t = threadIdx.x;
  const int rg = bid & 255;
  const int i = rg >> 2;
  const int j0 = (rg & 3) * 16;
  const int k0 = (bid >> 8) * 8;  // 0..56

  {  // stage a[r, i, j0..j0+15] for all r: 1024 floats
    const int r = t >> 2, jq = t & 3;
    float4 v = ((const float4*)(a + (size_t)r * 4096 + i * 64 + j0))[jq];
    ((float4*)lds_a)[r * 4 + jq] = v;
  }

  const float* bsrc = b + k0 * 64;  // row r at bsrc + r*4096 (512 floats used)

  // prologue: stage r-group 0 (16 KB, 4 x gl_lds per thread)
#pragma unroll
  for (int p = 0; p < 4; ++p) {
    const int idx = p * 256 + t;  // float4 index into the 16KB slab
    gl_lds16(bsrc + (size_t)(idx >> 7) * 4096 + (idx & 127) * 4,
             &((float4*)lds_b[0])[idx]);
  }
  WAIT_VM(0);
  __syncthreads();

  const int l = t & 63;
  const int jj = t >> 6;  // 0..3
  float acc[4][8];
#pragma unroll
  for (int jp = 0; jp < 4; ++jp)
#pragma unroll
    for (int kb = 0; kb < 8; ++kb) acc[jp][kb] = 0.f;

  for (int g = 0; g < 8; ++g) {
    const int cur = g & 1;
    if (g < 7) {  // prefetch next r-group into the other buffer
      const float* nb = bsrc + (size_t)(g + 1) * 8 * 4096;
#pragma unroll
      for (int p = 0; p < 4; ++p) {
        const int idx = p * 256 + t;
        gl_lds16(nb + (size_t)(idx >> 7) * 4096 + (idx & 127) * 4,
                 &((float4*)lds_b[cur ^ 1])[idx]);
      }
    }
#pragma unroll
    for (int rr = 0; rr < 8; ++rr) {
      float4 aj = ((const float4*)lds_a)[(g * 8 + rr) * 4 + jj];
      float bv[8];
#pragma unroll
      for (int kb = 0; kb < 8; ++kb) bv[kb] = lds_b[cur][rr * 512 + kb * 64 + l];
      const float av[4] = {aj.x, aj.y, aj.z, aj.w};
#pragma unroll
      for (int jp = 0; jp < 4; ++jp)
#pragma unroll
        for (int kb = 0; kb < 8; ++kb)
          acc[jp][kb] = fmaf(av[jp], bv[kb], acc[jp][kb]);
    }
    WAIT_VM(0);
    __syncthreads();
  }

  const int kt = (i * 64 + k0) >> 5;
  const int cw = (k0 & 31) >> 3;
#pragma unroll
  for (int jp = 0; jp < 4; ++jp) {
    const int j = j0 + jj * 4 + jp;
    const int n = j * 64 + l;
    const int blob = (n >> 7) * KT_COUNT + kt;
    const int pos = cw * 128 + (n & 127);
    short8 o;
#pragma unroll
    for (int kb = 0; kb < 8; ++kb) o[kb] = (short)f2bf(acc[jp][kb]);
    *(short8*)(Wp + (size_t)blob * 4096 + pos * 8) = o;
  }
}

// ---------------------------------------------------------------------------
// pack_x: LDS tile transpose. 2048 blocks x 512 threads, 32 KB LDS.
// Block = (M0 0..63, h 0..1, kg 0..15). Reads: wave = 2 rows x 1KB contig.
// XOR-swizzled LDS, conflict-free both sides. Writes: 1KB contig runs.
// Xp blob (M0, kt) = 8KB: chunk (c*128+mm) holds row mm, k=kt*32+c*8..+7.
// ---------------------------------------------------------------------------
__global__ __launch_bounds__(512) void pack_x_kernel(
    const float* __restrict__ x, unsigned short* __restrict__ Xp) {
  __shared__ short8 smem[2048];  // 32 KB: [64 rows][32 chunks]
  const int pid = blockIdx.x;
  const int M0 = pid >> 5;        // 0..63
  const int h = (pid >> 4) & 1;   // row half of the 128-row panel
  const int kg = pid & 15;        // 256-k group
  const int t = threadIdx.x;

  {
    const int rsub = t >> 5;  // 0..15
    const int col8 = t & 31;  // 16B chunk in the 256-k slice
#pragma unroll
    for (int p = 0; p < 4; ++p) {
      const int rr = p * 16 + rsub;  // 0..63
      const float* src =
          x + (size_t)(M0 * 128 + h * 64 + rr) * K_DIM + kg * 256 + col8 * 8;
      float4 v0 = ((const float4*)src)[0];
      float4 v1 = ((const float4*)src)[1];
      short8 o;
      o[0] = (short)f2bf(v0.x); o[1] = (short)f2bf(v0.y);
      o[2] = (short)f2bf(v0.z); o[3] = (short)f2bf(v0.w);
      o[4] = (short)f2bf(v1.x); o[5] = (short)f2bf(v1.y);
      o[6] = (short)f2bf(v1.z); o[7] = (short)f2bf(v1.w);
      smem[rr * 32 + (col8 ^ (rr & 31))] = o;
    }
  }
  __syncthreads();

  const int ml = t & 63;        // local row
  const int c = (t >> 6) & 3;   // k-chunk within K-step
  const int qh = t >> 8;        // 0..1: blob parity
#pragma unroll
  for (int q = 0; q < 4; ++q) {
    const int qq = q * 2 + qh;       // K-step within the kg group (0..7)
    const int cc = qq * 4 + c;       // chunk col in smem (0..31)
    short8 v = smem[ml * 32 + (cc ^ (ml & 31))];
    unsigned short* dst = Xp + (size_t)(M0 * KT_COUNT + kg * 8 + qq) * 4096 +
                          (size_t)(c * 128 + h * 64 + ml) * 8;
    *(short8*)dst = v;
  }
}

// ---------------------------------------------------------------------------
// GEMM (R1 schedule, 242-244us measured as 512 blocks): C = Xp@Wp^T + bias.
// 256x256 tile, BK=32, 512 threads (8 waves, 2M x 4N), acc[8][4].
// 4-deep LDS ring; prefetch distance 2; single counted vmcnt(4)/K-step.
// Now launched as 2 x 256 blocks with bofs so each batch is a separate
// dispatch (visibility threshold ~122us); bid = blockIdx.x + bofs.
// ---------------------------------------------------------------------------
__global__ __launch_bounds__(512, 2) void gemm_kernel(
    const unsigned short* __restrict__ Xp, const unsigned short* __restrict__ Wp,
    const float* __restrict__ bias, float* __restrict__ out, int bofs) {
  __shared__ short8 As[4][2][512];  // [ring buf][row half][chunk]  64 KiB
  __shared__ short8 Bs[4][2][512];  // [ring buf][col half][chunk]  64 KiB

  const int bid = blockIdx.x + bofs;
  const int xcd = bid & 7;
  const int pos = bid >> 3;            // 0..63
  const int N0 = xcd * 2 + (pos & 1);  // 0..15 (256-col panels)
  const int M0 = pos >> 1;             // 0..31 (256-row panels)

  const int t = threadIdx.x;
  const int wave = t >> 6, lane = t & 63;
  const int l16 = lane & 15, quad = lane >> 4;
  const int wm = wave & 1;   // A half (128 rows)
  const int wn = wave >> 1;  // 0..3 (64-col quarter)

  floatx4 acc[8][4];
#pragma unroll
  for (int mt = 0; mt < 8; ++mt)
#pragma unroll
    for (int nt = 0; nt < 4; ++nt) acc[mt][nt] = (floatx4){0.f, 0.f, 0.f, 0.f};

  const unsigned short* gA0 = Xp + (size_t)(M0 * 2 + 0) * KT_COUNT * 4096 + (size_t)t * 8;
  const unsigned short* gA1 = Xp + (size_t)(M0 * 2 + 1) * KT_COUNT * 4096 + (size_t)t * 8;
  const unsigned short* gB0 = Wp + (size_t)(N0 * 2 + 0) * KT_COUNT * 4096 + (size_t)t * 8;
  const unsigned short* gB1 = Wp + (size_t)(N0 * 2 + 1) * KT_COUNT * 4096 + (size_t)t * 8;

  // ---- prologue: stage K-steps 0 and 1 (8 loads), require step 0 landed.
  gl_lds16(gA0, &As[0][0][t]);
  gl_lds16(gA1, &As[0][1][t]);
  gl_lds16(gB0, &Bs[0][0][t]);
  gl_lds16(gB1, &Bs[0][1][t]);
  gl_lds16(gA0 + 4096, &As[1][0][t]);
  gl_lds16(gA1 + 4096, &As[1][1][t]);
  gl_lds16(gB0 + 4096, &Bs[1][0][t]);
  gl_lds16(gB1 + 4096, &Bs[1][1][t]);
  WAIT_VM(4);  // 4 newest (step 1) may stay in flight; step 0 complete
  BAR();

  const int ra = quad * 128 + l16;                  // A chunk base
  const int rb = quad * 128 + (wn & 1) * 64 + l16;  // B chunk base
  const int bh = wn >> 1;                           // B half

#pragma unroll 2
  for (int kt = 0; kt < KT_COUNT; ++kt) {
    const int tb = kt & 3;
    const int db = (kt + 2) & 3;
    const size_t soff =
        (size_t)((kt + 2 < KT_COUNT) ? kt + 2 : KT_COUNT - 1) * 4096;

    short8 bf[4], af[4];

    // ---------------- phase 0: B frags + A rows 0..63, stage A(t+2)
#pragma unroll
    for (int nt = 0; nt < 4; ++nt) bf[nt] = Bs[tb][bh][rb + nt * 16];
#pragma unroll
    for (int m = 0; m < 4; ++m) af[m] = As[tb][wm][ra + m * 16];
    gl_lds16(gA0 + soff, &As[db][0][t]);
    gl_lds16(gA1 + soff, &As[db][1][t]);
    BAR();
    WAIT_LGKM0();
    __builtin_amdgcn_sched_barrier(0);
    __builtin_amdgcn_s_setprio(1);
#pragma unroll
    for (int m = 0; m < 4; ++m)
#pragma unroll
      for (int nt = 0; nt < 4; ++nt)
        acc[m][nt] = __builtin_amdgcn_mfma_f32_16x16x32_bf16(
            af[m], bf[nt], acc[m][nt], 0, 0, 0);
    __builtin_amdgcn_s_setprio(0);
    __builtin_amdgcn_sched_barrier(0);
    BAR();

    // ---------------- phase 1: A rows 64..127, stage B(t+2), counted vmcnt
#pragma unroll
    for (int m = 0; m < 4; ++m) af[m] = As[tb][wm][ra + (4 + m) * 16];
    gl_lds16(gB0 + soff, &Bs[db][0][t]);
    gl_lds16(gB1 + soff, &Bs[db][1][t]);
    WAIT_VM(4);  // allow the 4 t+2 loads in flight; forces step t+1 landed
    BAR();
    WAIT_LGKM0();
    __builtin_amdgcn_sched_barrier(0);
    __builtin_amdgcn_s_setprio(1);
#pragma unroll
    for (int m = 0; m < 4; ++m)
#pragma unroll
      for (int nt = 0; nt < 4; ++nt)
        acc[4 + m][nt] = __builtin_amdgcn_mfma_f32_16x16x32_bf16(
            af[m], bf[nt], acc[4 + m][nt], 0, 0, 0);
    __builtin_amdgcn_s_setprio(0);
    __builtin_amdgcn_sched_barrier(0);
    BAR();
  }

  // ---- epilogue
  const int col_base = N0 * 256 + wn * 64;
  const int row_base = M0 * 256 + wm * 128;
#pragma unroll
  for (int nt = 0; nt < 4; ++nt) {
    const int col = col_base + nt * 16 + l16;
    const float bv = bias[col];
#pragma unroll
    for (int mt = 0; mt < 8; ++mt) {
      floatx4 v = acc[mt][nt];
#pragma unroll
      for (int r4 = 0; r4 < 4; ++r4) {
        const int row = row_base + mt * 16 + quad * 4 + r4;
        out[(size_t)row * N_DIM + col] = v[r4] + bv;
      }
    }
  }
}

extern "C" void kernel_launch(void* const* d_in, const int* in_sizes, int n_in,
                              void* d_out, int out_size, void* d_ws, size_t ws_size,
                              hipStream_t stream) {
  const float* x = (const float*)d_in[0];     // 8192*4096
  const float* a = (const float*)d_in[1];     // 64*64*64 (r,i,j)
  const float* b = (const float*)d_in[2];     // 64*64*64 (r,k,l)
  const float* bias = (const float*)d_in[3];  // 4096
  float* out = (float*)d_out;

  unsigned short* Xp = (unsigned short*)d_ws;        // 67MB
  unsigned short* Wp = Xp + (size_t)M_DIM * K_DIM;   // 33.5MB

  build_w_kernel<<<2048, 256, 0, stream>>>(a, b, Wp);
  pack_x_kernel<<<2048, 512, 0, stream>>>(x, Xp);   // measured twice:
  pack_x_kernel<<<2048, 512, 0, stream>>>(x, Xp);   // p = (total-g1-g2)-230
  gemm_kernel<<<256, 512, 0, stream>>>(Xp, Wp, bias, out, 0);
  gemm_kernel<<<256, 512, 0, stream>>>(Xp, Wp, bias, out, 256);
}

// Round 7
// 489.913 us; speedup vs baseline: 1.0700x; 1.0700x over previous
//
#include <hip/hip_runtime.h>
#include <hip/hip_bf16.h>

// KronLinear: out = x @ (sum_r kron(a_r, b_r)) + bias
// M=8192 tokens, K=4096=(i,k_b), N=4096=(j,l), RANK=64.
// R9: decode of R8 instrumentation: build_w ~101-129us AND pack_x(cold)
// ~101-129us (pack warm = 36us). Fixes:
//  - build_w_v2: register-blocked (128 acc/thread), b read as global float4
//    from L2 (1MB, resident) with r ping-pong; a staged in LDS (broadcast
//    b128). FMA:mem-instr 3.6 -> 14. Old version issued 576 LDS instr/thread
//    (8 scalar ds_read_b32 per 32 FMA) = LDS-issue-bound ~115us.
//  - pack_x_v2: 128-row x 256-k blocks (64KB LDS) so every 8KB blob is
//    written fully contiguous (old 64-row blocks interleaved two blocks'
//    1KB-at-2KB-stride half-blob writes across XCDs).
//  - gemm: back to single 512-block dispatch (R1 schedule, 244us measured).

#define M_DIM 8192
#define N_DIM 4096
#define K_DIM 4096
#define KT_COUNT 128   // K_DIM / 32

typedef __attribute__((ext_vector_type(8))) short short8;
typedef __attribute__((ext_vector_type(4))) float floatx4;

typedef __attribute__((address_space(1))) void gvoid_t;
typedef __attribute__((address_space(3))) void lvoid_t;

static __device__ __forceinline__ void gl_lds16(const void* g, const void* l) {
  __builtin_amdgcn_global_load_lds((gvoid_t*)(unsigned long long)g,
                                   (lvoid_t*)(unsigned int)(unsigned long long)l,
                                   16, 0, 0);
}

static __device__ __forceinline__ unsigned short f2bf(float f) {
  unsigned int u = __builtin_bit_cast(unsigned int, f);
  u = (u + 0x7fffu + ((u >> 16) & 1u)) >> 16;  // RNE
  return (unsigned short)u;
}

#define BAR() asm volatile("s_barrier" ::: "memory")
#define WAIT_VM(N) asm volatile("s_waitcnt vmcnt(" #N ")" ::: "memory")
#define WAIT_LGKM0() asm volatile("s_waitcnt lgkmcnt(0)" ::: "memory")

// ---------------------------------------------------------------------------
// build_w_v2: wT[n=(j*64+l)][i*64+kb] = sum_r a[r,i,j]*b[r,kb,l]
// 256 blocks x 512 threads. Block = (i 0..63, kq 0..3): all j, all l,
// kb = kq*16 .. +15. Thread t = (kbh = t>>8, j4 = (t>>4)&15, l4 = t&15):
// tile 4j x 4l x 8kb = 128 acc.
// a_i (16KB) staged in LDS via gl_lds; per r: 1 broadcast ds_read_b128 (a)
// + 8 global float4 (b, L2-resident), ping-pong over r; 128 FMA.
// Wp blob (T0, kt) = 8KB: chunk (c*128+n&127) holds 8 kb as short8.
// ---------------------------------------------------------------------------
__global__ __launch_bounds__(512, 2) void build_w_kernel(
    const float* __restrict__ a, const float* __restrict__ b,
    unsigned short* __restrict__ Wp) {
  __shared__ float lds_a[4096];  // 16 KB: [r][j] for this i
  const int bid = blockIdx.x;
  const int i = bid >> 2;
  const int kq = bid & 3;
  const int t = threadIdx.x;
  const int kbh = t >> 8;        // 0..1
  const int j4 = (t >> 4) & 15;  // j block
  const int l4 = t & 15;         // l block

  // stage a[r, i, 0..63] for all r: 4096 floats = 1024 f4, 2 per thread
#pragma unroll
  for (int p = 0; p < 2; ++p) {
    const int idx = p * 512 + t;              // float4 index
    const int r = idx >> 4, jq = idx & 15;
    gl_lds16(a + (size_t)r * 4096 + i * 64 + jq * 4, &((float4*)lds_a)[idx]);
  }
  WAIT_VM(0);
  __syncthreads();

  float acc[4][4][8];
#pragma unroll
  for (int jp = 0; jp < 4; ++jp)
#pragma unroll
    for (int lp = 0; lp < 4; ++lp)
#pragma unroll
      for (int kbi = 0; kbi < 8; ++kbi) acc[jp][lp][kbi] = 0.f;

  const float* bb = b + (kq * 16 + kbh * 8) * 64 + l4 * 4;

  float4 bv0[8], bv1[8];
#pragma unroll
  for (int kbi = 0; kbi < 8; ++kbi)
    bv0[kbi] = *(const float4*)(bb + kbi * 64);  // r = 0

#define BW_FMA(AV, BV)                                                   \
  do {                                                                   \
    const float av_[4] = {(AV).x, (AV).y, (AV).z, (AV).w};               \
    _Pragma("unroll") for (int jp = 0; jp < 4; ++jp) {                   \
      _Pragma("unroll") for (int kbi = 0; kbi < 8; ++kbi) {              \
        acc[jp][0][kbi] = fmaf(av_[jp], (BV)[kbi].x, acc[jp][0][kbi]);   \
        acc[jp][1][kbi] = fmaf(av_[jp], (BV)[kbi].y, acc[jp][1][kbi]);   \
        acc[jp][2][kbi] = fmaf(av_[jp], (BV)[kbi].z, acc[jp][2][kbi]);   \
        acc[jp][3][kbi] = fmaf(av_[jp], (BV)[kbi].w, acc[jp][3][kbi]);   \
      }                                                                  \
    }                                                                    \
  } while (0)

  for (int r = 0; r < 64; r += 2) {
    const float* b1 = bb + (size_t)(r + 1) * 4096;
#pragma unroll
    for (int kbi = 0; kbi < 8; ++kbi) bv1[kbi] = *(const float4*)(b1 + kbi * 64);
    float4 av0 = *(const float4*)&lds_a[r * 64 + j4 * 4];
    BW_FMA(av0, bv0);
    const int r2 = (r + 2 < 64) ? r + 2 : 0;  // clamped dead load on last iter
    const float* b2 = bb + (size_t)r2 * 4096;
#pragma unroll
    for (int kbi = 0; kbi < 8; ++kbi) bv0[kbi] = *(const float4*)(b2 + kbi * 64);
    float4 av1 = *(const float4*)&lds_a[(r + 1) * 64 + j4 * 4];
    BW_FMA(av1, bv1);
  }
#undef BW_FMA

  // write: 16 short8 chunks. k = i*64 + kq*16 + kbh*8 + kbi
  const int kt = i * 2 + (kq >> 1);
  const int c = (kq & 1) * 2 + kbh;
#pragma unroll
  for (int jp = 0; jp < 4; ++jp) {
#pragma unroll
    for (int lp = 0; lp < 4; ++lp) {
      const int n = (j4 * 4 + jp) * 64 + l4 * 4 + lp;
      const int blob = (n >> 7) * KT_COUNT + kt;
      const int pos = c * 128 + (n & 127);
      short8 o;
#pragma unroll
      for (int kbi = 0; kbi < 8; ++kbi) o[kbi] = (short)f2bf(acc[jp][lp][kbi]);
      *(short8*)(Wp + (size_t)blob * 4096 + pos * 8) = o;
    }
  }
}

// ---------------------------------------------------------------------------
// pack_x_v2: LDS tile transpose, full-blob writes. 1024 blocks x 512 thr,
// 64 KB LDS. Block = (M0 0..63, kg 0..15): rows M0*128..+127, k kg*256..+255.
// Read: 8 passes, wave = 2 rows x 512B contiguous; XOR-swizzle (col8^(rr&31)).
// Write: 8 passes; pass qq writes blob kt=kg*8+qq COMPLETE: thread t -> chunk
// t (c=t>>7, mm=t&127), 8KB contiguous; 64KB contiguous per block.
// Xp blob (M0, kt) = 8KB: chunk (c*128+mm) holds row mm, k=kt*32+c*8..+7.
// ---------------------------------------------------------------------------
__global__ __launch_bounds__(512) void pack_x_kernel(
    const float* __restrict__ x, unsigned short* __restrict__ Xp) {
  __shared__ short8 smem[4096];  // 64 KB: [128 rows][32 chunks]
  const int pid = blockIdx.x;
  const int M0 = pid >> 4;   // 0..63
  const int kg = pid & 15;   // 256-k group
  const int t = threadIdx.x;

  {
    const int rsub = t >> 5;  // 0..15
    const int col8 = t & 31;  // 16B chunk in the 256-k slice
#pragma unroll
    for (int p = 0; p < 8; ++p) {
      const int rr = p * 16 + rsub;  // 0..127
      const float* src =
          x + (size_t)(M0 * 128 + rr) * K_DIM + kg * 256 + col8 * 8;
      float4 v0 = ((const float4*)src)[0];
      float4 v1 = ((const float4*)src)[1];
      short8 o;
      o[0] = (short)f2bf(v0.x); o[1] = (short)f2bf(v0.y);
      o[2] = (short)f2bf(v0.z); o[3] = (short)f2bf(v0.w);
      o[4] = (short)f2bf(v1.x); o[5] = (short)f2bf(v1.y);
      o[6] = (short)f2bf(v1.z); o[7] = (short)f2bf(v1.w);
      smem[rr * 32 + (col8 ^ (rr & 31))] = o;
    }
  }
  __syncthreads();

  const int c = t >> 7, mm = t & 127;
  unsigned short* dst = Xp + (size_t)(M0 * KT_COUNT + kg * 8) * 4096 + t * 8;
#pragma unroll
  for (int qq = 0; qq < 8; ++qq) {
    short8 v = smem[mm * 32 + ((qq * 4 + c) ^ (mm & 31))];
    *(short8*)(dst + (size_t)qq * 4096) = v;
  }
}

// ---------------------------------------------------------------------------
// GEMM (R1 schedule, 242-244us measured): C = Xp @ Wp^T + bias.
// 256x256 tile, BK=32, 512 threads (8 waves, 2M x 4N), acc[8][4].
// 4-deep LDS ring; prefetch distance 2; single counted vmcnt(4)/K-step.
// XCD swizzle: bid&7 -> XCD owns 2 N-panels (4MB Wp slice pinned in its L2).
// ---------------------------------------------------------------------------
__global__ __launch_bounds__(512, 2) void gemm_kernel(
    const unsigned short* __restrict__ Xp, const unsigned short* __restrict__ Wp,
    const float* __restrict__ bias, float* __restrict__ out) {
  __shared__ short8 As[4][2][512];  // [ring buf][row half][chunk]  64 KiB
  __shared__ short8 Bs[4][2][512];  // [ring buf][col half][chunk]  64 KiB

  const int bid = blockIdx.x;
  const int xcd = bid & 7;
  const int pos = bid >> 3;            // 0..63
  const int N0 = xcd * 2 + (pos & 1);  // 0..15 (256-col panels)
  const int M0 = pos >> 1;             // 0..31 (256-row panels)

  const int t = threadIdx.x;
  const int wave = t >> 6, lane = t & 63;
  const int l16 = lane & 15, quad = lane >> 4;
  const int wm = wave & 1;   // A half (128 rows)
  const int wn = wave >> 1;  // 0..3 (64-col quarter)

  floatx4 acc[8][4];
#pragma unroll
  for (int mt = 0; mt < 8; ++mt)
#pragma unroll
    for (int nt = 0; nt < 4; ++nt) acc[mt][nt] = (floatx4){0.f, 0.f, 0.f, 0.f};

  const unsigned short* gA0 = Xp + (size_t)(M0 * 2 + 0) * KT_COUNT * 4096 + (size_t)t * 8;
  const unsigned short* gA1 = Xp + (size_t)(M0 * 2 + 1) * KT_COUNT * 4096 + (size_t)t * 8;
  const unsigned short* gB0 = Wp + (size_t)(N0 * 2 + 0) * KT_COUNT * 4096 + (size_t)t * 8;
  const unsigned short* gB1 = Wp + (size_t)(N0 * 2 + 1) * KT_COUNT * 4096 + (size_t)t * 8;

  // ---- prologue: stage K-steps 0 and 1 (8 loads), require step 0 landed.
  gl_lds16(gA0, &As[0][0][t]);
  gl_lds16(gA1, &As[0][1][t]);
  gl_lds16(gB0, &Bs[0][0][t]);
  gl_lds16(gB1, &Bs[0][1][t]);
  gl_lds16(gA0 + 4096, &As[1][0][t]);
  gl_lds16(gA1 + 4096, &As[1][1][t]);
  gl_lds16(gB0 + 4096, &Bs[1][0][t]);
  gl_lds16(gB1 + 4096, &Bs[1][1][t]);
  WAIT_VM(4);  // 4 newest (step 1) may stay in flight; step 0 complete
  BAR();

  const int ra = quad * 128 + l16;                  // A chunk base
  const int rb = quad * 128 + (wn & 1) * 64 + l16;  // B chunk base
  const int bh = wn >> 1;                           // B half

#pragma unroll 2
  for (int kt = 0; kt < KT_COUNT; ++kt) {
    const int tb = kt & 3;
    const int db = (kt + 2) & 3;
    const size_t soff =
        (size_t)((kt + 2 < KT_COUNT) ? kt + 2 : KT_COUNT - 1) * 4096;

    short8 bf[4], af[4];

    // ---------------- phase 0: B frags + A rows 0..63, stage A(t+2)
#pragma unroll
    for (int nt = 0; nt < 4; ++nt) bf[nt] = Bs[tb][bh][rb + nt * 16];
#pragma unroll
    for (int m = 0; m < 4; ++m) af[m] = As[tb][wm][ra + m * 16];
    gl_lds16(gA0 + soff, &As[db][0][t]);
    gl_lds16(gA1 + soff, &As[db][1][t]);
    BAR();
    WAIT_LGKM0();
    __builtin_amdgcn_sched_barrier(0);
    __builtin_amdgcn_s_setprio(1);
#pragma unroll
    for (int m = 0; m < 4; ++m)
#pragma unroll
      for (int nt = 0; nt < 4; ++nt)
        acc[m][nt] = __builtin_amdgcn_mfma_f32_16x16x32_bf16(
            af[m], bf[nt], acc[m][nt], 0, 0, 0);
    __builtin_amdgcn_s_setprio(0);
    __builtin_amdgcn_sched_barrier(0);
    BAR();

    // ---------------- phase 1: A rows 64..127, stage B(t+2), counted vmcnt
#pragma unroll
    for (int m = 0; m < 4; ++m) af[m] = As[tb][wm][ra + (4 + m) * 16];
    gl_lds16(gB0 + soff, &Bs[db][0][t]);
    gl_lds16(gB1 + soff, &Bs[db][1][t]);
    WAIT_VM(4);  // allow the 4 t+2 loads in flight; forces step t+1 landed
    BAR();
    WAIT_LGKM0();
    __builtin_amdgcn_sched_barrier(0);
    __builtin_amdgcn_s_setprio(1);
#pragma unroll
    for (int m = 0; m < 4; ++m)
#pragma unroll
      for (int nt = 0; nt < 4; ++nt)
        acc[4 + m][nt] = __builtin_amdgcn_mfma_f32_16x16x32_bf16(
            af[m], bf[nt], acc[4 + m][nt], 0, 0, 0);
    __builtin_amdgcn_s_setprio(0);
    __builtin_amdgcn_sched_barrier(0);
    BAR();
  }

  // ---- epilogue
  const int col_base = N0 * 256 + wn * 64;
  const int row_base = M0 * 256 + wm * 128;
#pragma unroll
  for (int nt = 0; nt < 4; ++nt) {
    const int col = col_base + nt * 16 + l16;
    const float bv = bias[col];
#pragma unroll
    for (int mt = 0; mt < 8; ++mt) {
      floatx4 v = acc[mt][nt];
#pragma unroll
      for (int r4 = 0; r4 < 4; ++r4) {
        const int row = row_base + mt * 16 + quad * 4 + r4;
        out[(size_t)row * N_DIM + col] = v[r4] + bv;
      }
    }
  }
}

extern "C" void kernel_launch(void* const* d_in, const int* in_sizes, int n_in,
                              void* d_out, int out_size, void* d_ws, size_t ws_size,
                              hipStream_t stream) {
  const float* x = (const float*)d_in[0];     // 8192*4096
  const float* a = (const float*)d_in[1];     // 64*64*64 (r,i,j)
  const float* b = (const float*)d_in[2];     // 64*64*64 (r,k,l)
  const float* bias = (const float*)d_in[3];  // 4096
  float* out = (float*)d_out;

  unsigned short* Xp = (unsigned short*)d_ws;        // 67MB
  unsigned short* Wp = Xp + (size_t)M_DIM * K_DIM;   // 33.5MB

  build_w_kernel<<<256, 512, 0, stream>>>(a, b, Wp);
  pack_x_kernel<<<1024, 512, 0, stream>>>(x, Xp);
  gemm_kernel<<<512, 512, 0, stream>>>(Xp, Wp, bias, out);
}